// Round 2
// 148.158 us; speedup vs baseline: 1.1706x; 1.1706x over previous
//
#include <hip/hip_runtime.h>
#include <hip/hip_bf16.h>

// TriangleAttentionStartingNode  B=1, N=256, C_Z=128, H=4, D=32, TOTAL=128
// Round 7: FULL FUSION (round-6 structure) + race fix.
//   Round-6 bug: stage32() for phase N+1 overwrote SCR while slower waves were
//   still reading phase-N weight frags (no barrier between last SCR read and
//   restage) -> corrupted Wv/Wg staging. Fix: __syncthreads() before each
//   restage (phase 2->3, 3->4).
//   prep:  pack W^T (Q pre-scaled) + Wo^T into MFMA-frag-order bf16
//   bias:  LN fused in-register + VALU dot with Wb -> BbF fp32 in attn-frag order
//   fused: block = pair-row i (grid 256, 512 thr, 160 KB LDS):
//          LN->regs; proj GEMM (weights staged 32KB at a time in SCR);
//          K & V^T live in swizzled LDS; Q bounced through LDS into per-wave
//          frags; G bounced through global in coalesced acc-order blobs
//          (same-block write+read, L2-hot); attention with bias preloaded
//          into MFMA acc, P per-wave in SCR; gvals bounced through LDS into
//          fused oproj; float4 stores + bo.

#define QSCALE 0.17677669529663687f  // 1/sqrt(32)

typedef __attribute__((ext_vector_type(8))) short bf16x8;
typedef __attribute__((ext_vector_type(4))) float f32x4;

__device__ __forceinline__ ushort f2bf(float f) {
    uint32_t u = __builtin_bit_cast(uint32_t, f);
    uint32_t r = (u + 0x7FFFu + ((u >> 16) & 1u)) >> 16;  // RNE
    return (ushort)r;
}
__device__ __forceinline__ float bf2f(ushort b) {
    return __builtin_bit_cast(float, ((uint32_t)b) << 16);
}
__device__ __forceinline__ uint pk2(float a, float b) {   // v_cvt_pk_bf16_f32
    union { __hip_bfloat162 h; uint u; } cv;
    cv.h = __float22bfloat162_rn(make_float2(a, b));
    return cv.u;
}

// ---------------------------------------------------------------------------
// prep: Wfrag[ct 0..32][ks 0..3][lane 0..63][j 0..7] bf16 where
//   n = ct*16 + (lane&15), k = ks*32 + (lane>>4)*8 + j, value = W^T[n][k].
//   n: 0..127 Wq*QSCALE, 128..255 Wk, 256..383 Wv, 384..511 Wg.
// WoFrag: same layout, 8 ct over Wo^T.   grid 320*256 = 65536 + 16384.
// ---------------------------------------------------------------------------
__global__ __launch_bounds__(256) void prep_kernel(
    const float* __restrict__ Wq, const float* __restrict__ Wk, const float* __restrict__ Wv,
    const float* __restrict__ Wg, const float* __restrict__ Wo,
    ushort* __restrict__ Wfrag, ushort* __restrict__ WoFrag)
{
    int idx = blockIdx.x * 256 + threadIdx.x;
    if (idx < 65536) {
        int j = idx & 7, lane = (idx >> 3) & 63, ks = (idx >> 9) & 3, ct = idx >> 11;
        int n = ct * 16 + (lane & 15);
        int k = ks * 32 + (lane >> 4) * 8 + j;
        float v;
        if (n < 128)      v = Wq[k * 128 + n] * QSCALE;
        else if (n < 256) v = Wk[k * 128 + (n - 128)];
        else if (n < 384) v = Wv[k * 128 + (n - 256)];
        else              v = Wg[k * 128 + (n - 384)];
        Wfrag[idx] = f2bf(v);
    } else {
        int idx2 = idx - 65536;
        int j = idx2 & 7, lane = (idx2 >> 3) & 63, ks = (idx2 >> 9) & 3, ct = idx2 >> 11;
        int n = ct * 16 + (lane & 15);
        int k = ks * 32 + (lane >> 4) * 8 + j;
        WoFrag[idx2] = f2bf(Wo[k * 128 + n]);
    }
}

// ---------------------------------------------------------------------------
// bias: grid 1024 x 256. Per wave 16 positions (lane m = row, quad = ch chunk).
// LN stats via shfl; bias_h = sum_c xn_c * Wb[c][h]; reduce across quads;
// quad==0 scatters fp32 in attn-frag order:
//   addr = (((h*16 + row/16)*16 + col/16)*64 + ((col&15)>>2)*16 + (row&15))*4 + (col&3)
// where row = j (query pos), col = k (key pos).
// ---------------------------------------------------------------------------
__global__ __launch_bounds__(256) void bias_kernel(
    const float* __restrict__ x, const float* __restrict__ gamma, const float* __restrict__ beta,
    const float* __restrict__ Wb, float* __restrict__ BbF)
{
    __shared__ float WbS[512];
    __shared__ float gS[128];
    __shared__ float bS[128];
    const int t = threadIdx.x;
    if (t < 128)      { *(f32x4*)&WbS[t * 4] = *(const f32x4*)(Wb + t * 4); }
    else if (t < 160) { int c = (t - 128) * 4; *(f32x4*)&gS[c] = *(const f32x4*)(gamma + c); }
    else if (t < 192) { int c = (t - 160) * 4; *(f32x4*)&bS[c] = *(const f32x4*)(beta + c); }
    __syncthreads();

    const int wave = t >> 6, lane = t & 63, m = lane & 15, quad = lane >> 4;
    const int p = blockIdx.x * 64 + wave * 16 + m;

    const float* rp0 = x + (size_t)p * 128;
    f32x4 xa[4][2];
    float sum = 0.f, ssq = 0.f;
#pragma unroll
    for (int ks = 0; ks < 4; ++ks) {
        xa[ks][0] = *(const f32x4*)(rp0 + ks * 32 + quad * 8);
        xa[ks][1] = *(const f32x4*)(rp0 + ks * 32 + quad * 8 + 4);
#pragma unroll
        for (int q4 = 0; q4 < 2; ++q4) {
            f32x4 v = xa[ks][q4];
            sum += v[0] + v[1] + v[2] + v[3];
            ssq += v[0]*v[0] + v[1]*v[1] + v[2]*v[2] + v[3]*v[3];
        }
    }
    sum += __shfl_xor(sum, 16); ssq += __shfl_xor(ssq, 16);
    sum += __shfl_xor(sum, 32); ssq += __shfl_xor(ssq, 32);
    const float mu   = sum * (1.f / 128.f);
    const float rstd = rsqrtf(ssq * (1.f / 128.f) - mu * mu + 1e-5f);

    float b0 = 0.f, b1 = 0.f, b2 = 0.f, b3 = 0.f;
#pragma unroll
    for (int ks = 0; ks < 4; ++ks) {
#pragma unroll
        for (int q4 = 0; q4 < 2; ++q4) {
            const int c = ks * 32 + quad * 8 + q4 * 4;
            f32x4 v = xa[ks][q4];
#pragma unroll
            for (int e = 0; e < 4; ++e) {
                float xn = (v[e] - mu) * rstd * gS[c + e] + bS[c + e];
                f32x4 w = *(const f32x4*)&WbS[(c + e) * 4];
                b0 += xn * w[0]; b1 += xn * w[1]; b2 += xn * w[2]; b3 += xn * w[3];
            }
        }
    }
    b0 += __shfl_xor(b0, 16); b1 += __shfl_xor(b1, 16); b2 += __shfl_xor(b2, 16); b3 += __shfl_xor(b3, 16);
    b0 += __shfl_xor(b0, 32); b1 += __shfl_xor(b1, 32); b2 += __shfl_xor(b2, 32); b3 += __shfl_xor(b3, 32);

    if (quad == 0) {
        const int row = p >> 8, col = p & 255;
        float bb[4] = {b0, b1, b2, b3};
#pragma unroll
        for (int r = 0; r < 4; ++r) {
            int addr = (((r * 16 + (row >> 4)) * 16 + (col >> 4)) * 64 +
                        ((col & 15) >> 2) * 16 + (row & 15)) * 4 + (col & 3);
            BbF[addr] = bb[r];
        }
    }
}

// ---------------------------------------------------------------------------
// fused: grid 256 (block = pair row i), 512 threads = 8 waves, 160 KB LDS.
// LDS: KL 64KB (K [h][k/2][64] swz; reused as Qtmp [256][128] swz, then
//      gvals [256][128] swz), VL 64KB (V^T [h][d][256] swz), SCR 32KB
//      (weight staging, then per-wave P scratch [64][32] j-paired swz).
// Wave w: head h = w>>1; attention units jq = (w&1)*2 + {0,1} (64 q-rows each).
// ---------------------------------------------------------------------------
__device__ __forceinline__ void stage32(ushort* dst, const ushort* src, int t) {
    const uint4* s = (const uint4*)src;
    uint4* d = (uint4*)dst;
#pragma unroll
    for (int c = 0; c < 4; ++c) d[c * 512 + t] = s[c * 512 + t];
}

__global__ __launch_bounds__(512, 2) void fused_kernel(
    const float* __restrict__ x, const float* __restrict__ gamma, const float* __restrict__ beta,
    const ushort* __restrict__ Wfrag, const ushort* __restrict__ WoFrag,
    const float* __restrict__ bg, const float* __restrict__ bo,
    const float* __restrict__ BbF, ushort* __restrict__ Gg, float* __restrict__ out)
{
    extern __shared__ __align__(16) ushort smem[];
    ushort* KL  = smem;            // 32768 ushorts
    ushort* VL  = smem + 32768;    // 32768 ushorts
    ushort* SCR = smem + 65536;    // 16384 ushorts

    const int t = threadIdx.x;
    const int wave = t >> 6, lane = t & 63, m = lane & 15, quad = lane >> 4;
    const int i = blockIdx.x;

    // ---- Phase 0: LN -> per-wave B-frags (32 positions per wave) ----
    bf16x8 xf[2][4];
#pragma unroll
    for (int grp = 0; grp < 2; ++grp) {
        const int j = wave * 32 + grp * 16 + m;
        const float* rp0 = x + (size_t)(i * 256 + j) * 128;
        f32x4 xa[4][2];
        float sum = 0.f, ssq = 0.f;
#pragma unroll
        for (int ks = 0; ks < 4; ++ks) {
            xa[ks][0] = *(const f32x4*)(rp0 + ks * 32 + quad * 8);
            xa[ks][1] = *(const f32x4*)(rp0 + ks * 32 + quad * 8 + 4);
#pragma unroll
            for (int q4 = 0; q4 < 2; ++q4) {
                f32x4 v = xa[ks][q4];
                sum += v[0] + v[1] + v[2] + v[3];
                ssq += v[0]*v[0] + v[1]*v[1] + v[2]*v[2] + v[3]*v[3];
            }
        }
        sum += __shfl_xor(sum, 16); ssq += __shfl_xor(ssq, 16);
        sum += __shfl_xor(sum, 32); ssq += __shfl_xor(ssq, 32);
        const float mu   = sum * (1.f / 128.f);
        const float rstd = rsqrtf(ssq * (1.f / 128.f) - mu * mu + 1e-5f);
#pragma unroll
        for (int ks = 0; ks < 4; ++ks) {
            union { bf16x8 v; uint u[4]; } xu;
#pragma unroll
            for (int q4 = 0; q4 < 2; ++q4) {
                const int c = ks * 32 + quad * 8 + q4 * 4;
                f32x4 g4 = *(const f32x4*)(gamma + c);
                f32x4 b4 = *(const f32x4*)(beta + c);
                f32x4 v = xa[ks][q4];
                float n0 = (v[0] - mu) * rstd * g4[0] + b4[0];
                float n1 = (v[1] - mu) * rstd * g4[1] + b4[1];
                float n2 = (v[2] - mu) * rstd * g4[2] + b4[2];
                float n3 = (v[3] - mu) * rstd * g4[3] + b4[3];
                xu.u[q4 * 2]     = pk2(n0, n1);
                xu.u[q4 * 2 + 1] = pk2(n2, n3);
            }
            xf[grp][ks] = xu.v;
        }
    }

    // ---- Phase 1: Q projection, bounce through KL as Qtmp [256][128] swz ----
    stage32(SCR, Wfrag, t);            // cts 0..7 (Wq, pre-scaled)
    __syncthreads();
#pragma unroll
    for (int ct = 0; ct < 8; ++ct) {
        bf16x8 wfr[4];
#pragma unroll
        for (int ks = 0; ks < 4; ++ks) wfr[ks] = ((const bf16x8*)SCR)[(ct * 4 + ks) * 64 + lane];
#pragma unroll
        for (int grp = 0; grp < 2; ++grp) {
            f32x4 acc = (f32x4){0.f, 0.f, 0.f, 0.f};
#pragma unroll
            for (int ks = 0; ks < 4; ++ks)
                acc = __builtin_amdgcn_mfma_f32_16x16x32_bf16(wfr[ks], xf[grp][ks], acc, 0, 0, 0);
            const int pj = wave * 32 + grp * 16 + m;
            const int c0 = ct * 16 + quad * 4;
            const int idx = (pj * 128 + c0) ^ ((pj & 7) << 3);
            uint2 u; u.x = pk2(acc[0], acc[1]); u.y = pk2(acc[2], acc[3]);
            *(uint2*)(KL + idx) = u;
        }
    }
    __syncthreads();                   // fences phase-1 SCR reads AND Qtmp writes

    const int h = wave >> 1;                // this wave's head
    const int jb = (wave & 1) * 128;        // this wave's 128-row j range
    bf16x8 qf[8];                           // B-frags: lane=j, elems=d
#pragma unroll
    for (int jt8 = 0; jt8 < 8; ++jt8) {
        const int j = jb + jt8 * 16 + m;
        const int idx = (j * 128 + h * 32 + quad * 8) ^ ((j & 7) << 3);
        qf[jt8] = *(const bf16x8*)(KL + idx);
    }

    // ---- Phase 2: K projection -> KL [h][k/2][64] swz ----
    stage32(SCR, Wfrag + 16384, t);    // cts 8..15 (Wk)
    __syncthreads();                   // fences qf reads before KL overwrite
#pragma unroll
    for (int ct = 0; ct < 8; ++ct) {
        bf16x8 wfr[4];
#pragma unroll
        for (int ks = 0; ks < 4; ++ks) wfr[ks] = ((const bf16x8*)SCR)[(ct * 4 + ks) * 64 + lane];
        const int hk = ct >> 1;
        const int d0 = (ct & 1) * 16 + quad * 4;
#pragma unroll
        for (int grp = 0; grp < 2; ++grp) {
            f32x4 acc = (f32x4){0.f, 0.f, 0.f, 0.f};
#pragma unroll
            for (int ks = 0; ks < 4; ++ks)
                acc = __builtin_amdgcn_mfma_f32_16x16x32_bf16(wfr[ks], xf[grp][ks], acc, 0, 0, 0);
            const int k = wave * 32 + grp * 16 + m;
            const int idx = (hk * 8192 + (k >> 1) * 64 + (k & 1) * 32 + d0) ^ (((k >> 1) & 7) << 3);
            uint2 u; u.x = pk2(acc[0], acc[1]); u.y = pk2(acc[2], acc[3]);
            *(uint2*)(KL + idx) = u;
        }
    }

    // ---- Phase 3: V projection -> VL [h][d][256] swz (transposed) ----
    __syncthreads();                   // RACE FIX: phase-2 SCR reads done before restage
    stage32(SCR, Wfrag + 32768, t);    // cts 16..23 (Wv)
    __syncthreads();
#pragma unroll
    for (int ct = 0; ct < 8; ++ct) {
        bf16x8 wfr[4];
#pragma unroll
        for (int ks = 0; ks < 4; ++ks) wfr[ks] = ((const bf16x8*)SCR)[(ct * 4 + ks) * 64 + lane];
        const int hv = ct >> 1;
        const int d0 = (ct & 1) * 16 + quad * 4;
#pragma unroll
        for (int grp = 0; grp < 2; ++grp) {
            f32x4 acc = (f32x4){0.f, 0.f, 0.f, 0.f};
#pragma unroll
            for (int ks = 0; ks < 4; ++ks)
                acc = __builtin_amdgcn_mfma_f32_16x16x32_bf16(wfr[ks], xf[grp][ks], acc, 0, 0, 0);
            const int k = wave * 32 + grp * 16 + m;
#pragma unroll
            for (int r = 0; r < 4; ++r) {
                const int d = d0 + r;
                const int idx = ((hv * 32 + d) * 256 + k) ^ ((d & 7) << 3);
                VL[idx] = f2bf(acc[r]);
            }
        }
    }

    // ---- Phase 4: G projection -> global blob, coalesced acc-order ----
    __syncthreads();                   // RACE FIX: phase-3 SCR reads done before restage
    stage32(SCR, Wfrag + 49152, t);    // cts 24..31 (Wg)
    __syncthreads();
#pragma unroll
    for (int ct = 0; ct < 8; ++ct) {
        bf16x8 wfr[4];
#pragma unroll
        for (int ks = 0; ks < 4; ++ks) wfr[ks] = ((const bf16x8*)SCR)[(ct * 4 + ks) * 64 + lane];
        const int c0 = ct * 16 + quad * 4;
        f32x4 bg4 = *(const f32x4*)(bg + c0);
#pragma unroll
        for (int grp = 0; grp < 2; ++grp) {
            f32x4 acc = (f32x4){0.f, 0.f, 0.f, 0.f};
#pragma unroll
            for (int ks = 0; ks < 4; ++ks)
                acc = __builtin_amdgcn_mfma_f32_16x16x32_bf16(wfr[ks], xf[grp][ks], acc, 0, 0, 0);
            float z0 = 1.f / (1.f + __expf(-(acc[0] + bg4[0])));
            float z1 = 1.f / (1.f + __expf(-(acc[1] + bg4[1])));
            float z2 = 1.f / (1.f + __expf(-(acc[2] + bg4[2])));
            float z3 = 1.f / (1.f + __expf(-(acc[3] + bg4[3])));
            uint2 u; u.x = pk2(z0, z1); u.y = pk2(z2, z3);
            const int gidx = (((wave * 8 + ct) * 2 + grp) * 64 + lane) * 4;
            *(uint2*)(Gg + (size_t)i * 32768 + gidx) = u;
        }
    }
    __syncthreads();    // K, V, Gg visible to all; SCR free -> per-wave P scratch

    // ---- attention: 2 units per wave (h, jq), 64 q-rows each ----
    ushort* Pw = SCR + wave * 2048;
    f32x4 O[2][4][2];
    float lsum[2][4];
#pragma unroll
    for (int u = 0; u < 2; ++u)
#pragma unroll
        for (int jt = 0; jt < 4; ++jt) {
            O[u][jt][0] = (f32x4){0.f, 0.f, 0.f, 0.f};
            O[u][jt][1] = (f32x4){0.f, 0.f, 0.f, 0.f};
            lsum[u][jt] = 0.f;
        }

#pragma unroll
    for (int u = 0; u < 2; ++u) {
        const int jq = (wave & 1) * 2 + u;
        for (int kh = 0; kh < 8; ++kh) {
            const int k0 = kh * 32;
            bf16x8 kf[2];                       // A-frags: lane=k, elems=d
#pragma unroll
            for (int kk = 0; kk < 2; ++kk) {
                const int k = k0 + kk * 16 + m;
                const int idx = (h * 8192 + (k >> 1) * 64 + (k & 1) * 32 + quad * 8) ^ (((k >> 1) & 7) << 3);
                kf[kk] = *(const bf16x8*)(KL + idx);
            }
#pragma unroll
            for (int jt = 0; jt < 4; ++jt) {
                const int jtg = jq * 4 + jt;
#pragma unroll
                for (int kk = 0; kk < 2; ++kk) {
                    const int ktg = kh * 2 + kk;
                    f32x4 S = *(const f32x4*)(BbF + (((h * 16 + jtg) * 16 + ktg) * 64 + lane) * 4);
                    S = __builtin_amdgcn_mfma_f32_16x16x32_bf16(kf[kk], qf[u * 4 + jt], S, 0, 0, 0);
                    float p0 = __expf(S[0]), p1 = __expf(S[1]);
                    float p2 = __expf(S[2]), p3 = __expf(S[3]);
                    lsum[u][jt] += p0 + p1 + p2 + p3;
                    const int jl = jt * 16 + m;
                    const int pidx = ((jl >> 1) * 64 + (jl & 1) * 32 + kk * 16 + quad * 4) ^ (((jl >> 1) & 7) << 3);
                    uint2 up; up.x = pk2(p0, p1); up.y = pk2(p2, p3);
                    *(uint2*)(Pw + pidx) = up;
                }
            }
            bf16x8 vf[2], pf[4];
#pragma unroll
            for (int dt = 0; dt < 2; ++dt) {    // A-frags: lane=d, elems=k
                const int d = dt * 16 + m;
                const int idx = ((h * 32 + d) * 256 + k0 + quad * 8) ^ ((d & 7) << 3);
                vf[dt] = *(const bf16x8*)(VL + idx);
            }
#pragma unroll
            for (int jt = 0; jt < 4; ++jt) {    // B-frags: lane=j, elems=k
                const int jl = jt * 16 + m;
                const int pidx = ((jl >> 1) * 64 + (jl & 1) * 32 + quad * 8) ^ (((jl >> 1) & 7) << 3);
                pf[jt] = *(const bf16x8*)(Pw + pidx);
            }
#pragma unroll
            for (int jt = 0; jt < 4; ++jt)
#pragma unroll
                for (int dt = 0; dt < 2; ++dt)
                    O[u][jt][dt] = __builtin_amdgcn_mfma_f32_16x16x32_bf16(
                        vf[dt], pf[jt], O[u][jt][dt], 0, 0, 0);
        }
    }

    // row sums across quads
#pragma unroll
    for (int u = 0; u < 2; ++u)
#pragma unroll
        for (int jt = 0; jt < 4; ++jt) {
            float s = lsum[u][jt];
            s += __shfl_xor(s, 16);
            s += __shfl_xor(s, 32);
            lsum[u][jt] = 1.f / s;
        }

    __syncthreads();    // attention done: KL & SCR reusable

    // ---- epilogue: gvals = G * O / sum -> KL [256][128] swz ----
#pragma unroll
    for (int u = 0; u < 2; ++u) {
        const int jq = (wave & 1) * 2 + u;
#pragma unroll
        for (int jt = 0; jt < 4; ++jt) {
            const int j = jq * 64 + jt * 16 + m;
            const float rl = lsum[u][jt];
#pragma unroll
            for (int dt = 0; dt < 2; ++dt) {
                const int c0 = h * 32 + dt * 16 + quad * 4;
                const int gaddr = ((((j >> 5) * 8 + (h * 2 + dt)) * 2 + ((j >> 4) & 1)) * 64 + quad * 16 + m) * 4;
                ushort4 gv = *(const ushort4*)(Gg + (size_t)i * 32768 + gaddr);
                float v0 = O[u][jt][dt][0] * rl * bf2f(gv.x);
                float v1 = O[u][jt][dt][1] * rl * bf2f(gv.y);
                float v2 = O[u][jt][dt][2] * rl * bf2f(gv.z);
                float v3 = O[u][jt][dt][3] * rl * bf2f(gv.w);
                const int idx = (j * 128 + c0) ^ ((j & 7) << 3);
                uint2 uo; uo.x = pk2(v0, v1); uo.y = pk2(v2, v3);
                *(uint2*)(KL + idx) = uo;
            }
        }
    }

    stage32(SCR, WoFrag, t);
    __syncthreads();    // gvals + WoFrag visible

    // ---- oproj: A = WoFrag, B = gvals-frags from LDS -> float4 stores ----
    bf16x8 gf[2][4];
#pragma unroll
    for (int grp = 0; grp < 2; ++grp) {
        const int pl = wave * 32 + grp * 16 + m;
#pragma unroll
        for (int ks = 0; ks < 4; ++ks) {
            const int idx = (pl * 128 + ks * 32 + quad * 8) ^ ((pl & 7) << 3);
            gf[grp][ks] = *(const bf16x8*)(KL + idx);
        }
    }
#pragma unroll
    for (int ct = 0; ct < 8; ++ct) {
        bf16x8 wfr[4];
#pragma unroll
        for (int ks = 0; ks < 4; ++ks) wfr[ks] = ((const bf16x8*)SCR)[(ct * 4 + ks) * 64 + lane];
        const int c0 = ct * 16 + quad * 4;
        f32x4 bov = *(const f32x4*)(bo + c0);
#pragma unroll
        for (int grp = 0; grp < 2; ++grp) {
            f32x4 acc = (f32x4){0.f, 0.f, 0.f, 0.f};
#pragma unroll
            for (int ks = 0; ks < 4; ++ks)
                acc = __builtin_amdgcn_mfma_f32_16x16x32_bf16(wfr[ks], gf[grp][ks], acc, 0, 0, 0);
            const int p = i * 256 + wave * 32 + grp * 16 + m;
            float4 vout = make_float4(acc[0] + bov[0], acc[1] + bov[1],
                                      acc[2] + bov[2], acc[3] + bov[3]);
            *(float4*)(out + (size_t)p * 128 + c0) = vout;
        }
    }
}

// ---------------------------------------------------------------------------
extern "C" void kernel_launch(void* const* d_in, const int* in_sizes, int n_in,
                              void* d_out, int out_size, void* d_ws, size_t ws_size,
                              hipStream_t stream) {
    const float* x     = (const float*)d_in[0];
    const float* gamma = (const float*)d_in[1];
    const float* beta  = (const float*)d_in[2];
    const float* Wq    = (const float*)d_in[3];
    const float* Wk    = (const float*)d_in[4];
    const float* Wv    = (const float*)d_in[5];
    const float* Wb    = (const float*)d_in[6];
    const float* Wg    = (const float*)d_in[7];
    const float* bg    = (const float*)d_in[8];
    const float* Wo    = (const float*)d_in[9];
    const float* bo    = (const float*)d_in[10];

    ushort* ws      = (ushort*)d_ws;
    ushort* Wfrag   = ws;                        // 65536 ushorts
    ushort* WoFragp = ws + 65536;                // 16384 ushorts
    ushort* Gg      = ws + 81920;                // 8388608 ushorts (16 MB)
    float*  BbF     = (float*)(ws + 81920 + 8388608);  // 262144 fp32 (1 MB)

    static bool attr_set = false;
    if (!attr_set) {
        hipFuncSetAttribute((const void*)fused_kernel,
                            hipFuncAttributeMaxDynamicSharedMemorySize, 163840);
        attr_set = true;
    }

    prep_kernel<<<320, 256, 0, stream>>>(Wq, Wk, Wv, Wg, Wo, Wfrag, WoFragp);
    bias_kernel<<<1024, 256, 0, stream>>>(x, gamma, beta, Wb, BbF);
    fused_kernel<<<256, 512, 163840, stream>>>(x, gamma, beta, Wfrag, WoFragp,
                                               bg, bo, BbF, Gg, (float*)d_out);
}